// Round 11
// baseline (3329.069 us; speedup 1.0000x reference)
//
#include <hip/hip_runtime.h>
#include <stdint.h>

#define B_  128
#define T_  512
#define H_  512
#define G3  1536

typedef __attribute__((ext_vector_type(8))) short bf16x8;
typedef __attribute__((ext_vector_type(4))) short bf16x4;
typedef __attribute__((ext_vector_type(4))) float f32x4;

#define MFMA16(a,b,c) __builtin_amdgcn_mfma_f32_16x16x32_bf16((a),(b),(c),0,0,0)

__device__ __forceinline__ unsigned short f2bf(float f) {
  union { float f; unsigned u; } v; v.f = f;
  unsigned r = v.u + 0x7FFFu + ((v.u >> 16) & 1u);
  return (unsigned short)(r >> 16);
}
__device__ __forceinline__ float bf2f(unsigned short u) {
  union { unsigned u; float f; } v; v.u = ((unsigned)u) << 16; return v.f;
}
__device__ __forceinline__ float sigm_f(float x) { return 1.f / (1.f + __expf(-x)); }
__device__ __forceinline__ float tanh_f(float x) { float e = __expf(2.f * x); return 1.f - 2.f / (e + 1.f); }

// ---------------- K0: cast weights to bf16 + zero barrier flags ----------------
__launch_bounds__(256)
__global__ void k_cast(const float* __restrict__ Wih_f, const float* __restrict__ Wih_b,
                       const float* __restrict__ Whh_f, const float* __restrict__ Whh_b,
                       const float* __restrict__ Wp,
                       unsigned short* __restrict__ Wih, unsigned short* __restrict__ Whh,
                       unsigned short* __restrict__ Wpb, unsigned* __restrict__ flags) {
  int idx = blockIdx.x * 256 + threadIdx.x;
  if (idx < 65536) flags[idx] = 0;          // [T][128] flag rows; row 511 = ctrl
  if (idx < 1572864) {            // Wih: [2][1536][512]
    float v = (idx < 786432) ? Wih_f[idx] : Wih_b[idx - 786432];
    Wih[idx] = f2bf(v);
  } else if (idx < 3145728) {     // Whh: [2][1536][512]
    int i2 = idx - 1572864;
    float v = (i2 < 786432) ? Whh_f[i2] : Whh_b[i2 - 786432];
    Whh[i2] = f2bf(v);
  } else if (idx < 3670016) {     // Wp: [512][1024]
    int i3 = idx - 3145728;
    Wpb[i3] = f2bf(Wp[i3]);
  }
}

// ---------------- K1: gather embedding -> x_bf [65536][512] ----------------
__launch_bounds__(256)
__global__ void k_gather(const int* __restrict__ tokens, const float* __restrict__ emb,
                         unsigned short* __restrict__ xbf) {
  int row = blockIdx.x * 4 + (threadIdx.x >> 6);
  int lane = threadIdx.x & 63;
  int tok = tokens[row];
  const float4* src = (const float4*)(emb + (size_t)tok * 512);
  float4 v0 = src[lane * 2], v1 = src[lane * 2 + 1];
  bf16x8 pk;
  pk[0] = (short)f2bf(v0.x); pk[1] = (short)f2bf(v0.y);
  pk[2] = (short)f2bf(v0.z); pk[3] = (short)f2bf(v0.w);
  pk[4] = (short)f2bf(v1.x); pk[5] = (short)f2bf(v1.y);
  pk[6] = (short)f2bf(v1.z); pk[7] = (short)f2bf(v1.w);
  *(bf16x8*)&xbf[(size_t)row * 512 + lane * 8] = pk;
}

// ---------------- K2: persistent bidirectional GRU recurrence (XCD-local) ----
// v11 = v6 exact (keepers deleted - R8/R10 proved both neutral) + two
// instruction-local critical-path fixes (NO protocol change):
//  (a) FIFO-vmcnt fix: v6's poll issued its first flag sample AFTER the 16
//      x-prefetch loads, so the sample's vmcnt(0) waited for ALL x loads
//      (~L3 latency) before the flag could be inspected - every step. Now
//      the sample issues BEFORE the x loads and waits with counted
//      vmcnt(17): exactly 17 ops (16 x + 1 warm) are younger, so the wait
//      completes when the FLAG is done, x still in flight. "+v" constraint
//      + sched_barrier(0) pin the check after the wait (rule #18). Lanes
//      seeing 0 fall into the proven vmcnt(0) retry loop.
//  (b) Flag-line warming: each step's flag row is a fresh 128B line never
//      touched by this XCD's L2 (zeroed by k_cast on other XCDs) - the
//      producer store pays a cold write-allocate and the poll a cold miss
//      (~900cy each) on the critical path. A discarded sc0 load of row t
//      (issued YOUNGEST, always - incl. t=511/ctrl row, keeping the
//      vmcnt(17) count invariant) pulls the line into L2 a full step ahead.
// Everything else byte-identical to v6 (3.09ms k_rec): runtime XCD claim,
// per-t flag rows, x prefetch before poll (R7), weights in LDS, two
// barriers/step, sc0 L2-local h exchange, outb after flag.
__launch_bounds__(256, 1)
__global__ void k_rec(const unsigned short* __restrict__ xbf,
                      const unsigned short* __restrict__ Wih,
                      const unsigned short* __restrict__ Whh,
                      const float* __restrict__ bih_f, const float* __restrict__ bih_b,
                      const float* __restrict__ bhh_f, const float* __restrict__ bhh_b,
                      const int* __restrict__ lengths,
                      unsigned short* __restrict__ hbuf,   // [2 buf][2 dir][128][512] bf16
                      unsigned short* __restrict__ outb,   // [65536][1024] bf16
                      unsigned* __restrict__ flags) {      // [512][128]; row 511 = ctrl
  __shared__ bf16x8 wlds[6][16][64];                 // 98304 B -> 1 block/CU
  __shared__ unsigned short htile[4][256];
  __shared__ unsigned short otile[4][256];
  __shared__ int role_s[2];

  unsigned* ctrl = flags + 511 * 128;

  if (threadIdx.x == 0) {
    unsigned xcd;
    asm volatile("s_getreg_b32 %0, hwreg(HW_REG_XCC_ID)" : "=s"(xcd));
    xcd &= 7u;
    unsigned slot = atomicAdd(&ctrl[xcd], 1u);      // device-scope (G12)
    unsigned gv;
    if (slot == 0u) {
      gv = atomicAdd(&ctrl[8], 1u) + 1u;            // this XCD claims a group
      __hip_atomic_store(&ctrl[16u + xcd], gv, __ATOMIC_RELAXED, __HIP_MEMORY_SCOPE_AGENT);
    } else {
      do {
        gv = __hip_atomic_load(&ctrl[16u + xcd], __ATOMIC_RELAXED, __HIP_MEMORY_SCOPE_AGENT);
      } while (gv == 0u);
    }
    int gq = (int)gv - 1;
    role_s[0] = (gq < 4 && slot < 32u) ? gq : -1;
    role_s[1] = (int)(slot & 31u);
  }
  __syncthreads();
  int g = role_s[0];
  if (g < 0) return;                  // surplus block or unclaimed XCD
  int j5 = role_s[1];

  int tid = threadIdx.x;
  int lane = tid & 63, w = tid >> 6;
  int quad = lane >> 4, l15 = lane & 15;
  int dir = g >> 1, mh = g & 1;
  int j0 = j5 << 4;
  int jg = j0 + l15;
  int rb = mh * 64 + w * 16;          // this wave's 16 batch rows

  const unsigned short* wih_g = Wih + (size_t)dir * (G3 * H_);
  const unsigned short* whh_g = Whh + (size_t)dir * (G3 * H_);
  const float* bih = dir ? bih_b : bih_f;
  const float* bhh = dir ? bhh_b : bhh_f;
  float b_r  = bih[jg] + bhh[jg];
  float b_z  = bih[512 + jg] + bhh[512 + jg];
  float b_in = bih[1024 + jg];
  float b_hn = bhh[1024 + jg];

  // ---- stage all 6 gate-weight fragment tables into LDS (one time) ----
  for (int gi = w; gi < 6; gi += 4) {
    const unsigned short* base =
        (gi < 3 ? wih_g : whh_g) + (size_t)((gi % 3) * 512 + j0 + (lane & 15)) * 512;
    for (int s = 0; s < 16; ++s)
      wlds[gi][s][lane] = *(const bf16x8*)&base[s * 32 + (lane >> 4) * 8];
  }
  __syncthreads();

  int b0 = rb + l15;                 // A-frag row
  int L0 = lengths[b0];
  int Lg[4];
  #pragma unroll
  for (int r = 0; r < 4; ++r) Lg[r] = lengths[rb + 4 * quad + r];
  int bs = rb + (lane >> 2);         // store-phase row
  int Ls = lengths[bs];
  int jp = lane & 3;

  unsigned short* hb = hbuf + (size_t)dir * (B_ * H_);
  float hreg[4] = {};                // f32 master copy of own (b, j) hidden state

  // prologue: x fragments for t=0
  bf16x8 ax[16];
  {
    int tx0 = dir ? (L0 - 1) : 0;    // L0 >= T/2 >= 1
    const unsigned short* xr = xbf + ((size_t)b0 * T_ + tx0) * 512;
    #pragma unroll
    for (int s = 0; s < 16; ++s) ax[s] = *(const bf16x8*)&xr[s * 32 + quad * 8];
  }

  #pragma clang loop unroll(disable)
  for (int t = 0; t < T_; ++t) {
    const unsigned short* hc = hb + (size_t)(t & 1) * (2 * B_ * H_);
    unsigned short* hnx      = hb + (size_t)((t & 1) ^ 1) * (2 * B_ * H_);

    f32x4 acc_r = {0.f,0.f,0.f,0.f}, acc_z = {0.f,0.f,0.f,0.f};
    f32x4 acc_n = {0.f,0.f,0.f,0.f}, acc_h = {0.f,0.f,0.f,0.f};

    // ---- (1) input GEMM for step t: x from regs, Wih from LDS
    #pragma unroll
    for (int s = 0; s < 16; ++s) {
      acc_r = MFMA16(ax[s], wlds[0][s][lane], acc_r);
      acc_z = MFMA16(ax[s], wlds[1][s][lane], acc_z);
      acc_n = MFMA16(ax[s], wlds[2][s][lane], acc_n);
    }

    // ---- (1a) first flag sample: issued BEFORE the x loads so the counted
    //           wait below completes on the FLAG, not on the x drain.
    unsigned pv0 = 1u;
    if (t > 0 && w == 0) {
      const unsigned* fp0 = &flags[(size_t)(t - 1) * 128 + g * 32 + (lane & 31)];
      asm volatile("global_load_dword %0, %1, off sc0"
                   : "=v"(pv0) : "v"(fp0) : "memory");
    }

    // ---- (1b) prefetch x for t+1 BEFORE the poll (R7: after = 2.7x regress)
    {
      int tn = (t + 1 < T_) ? (t + 1) : t;
      int tx1 = dir ? ((tn < L0) ? (L0 - 1 - tn) : 0) : tn;
      const unsigned short* xr1 = xbf + ((size_t)b0 * T_ + tx1) * 512;
      #pragma unroll
      for (int s = 0; s < 16; ++s) ax[s] = *(const bf16x8*)&xr1[s * 32 + quad * 8];
    }

    // ---- (1c) warm this step's flag row (stored by producers at end of
    //           step t, polled at t+1). Issued YOUNGEST and ALWAYS (t=511
    //           hits the ctrl row, harmless) so the vmcnt(17) count holds.
    if (w == 0) {
      unsigned wv;
      const unsigned* wp = &flags[(size_t)t * 128 + g * 32 + (lane & 31)];
      asm volatile("global_load_dword %0, %1, off sc0"
                   : "=v"(wv) : "v"(wp) : "memory");
      asm volatile("" :: "v"(wv));    // keep alive, result discarded (rule #17)
    }

    if (t > 0) {
      // ---- (2) counted wait: 17 ops younger than the flag sample (16 x +
      //          1 warm) -> vmcnt(17) completes exactly when the sample is
      //          done. "+v" makes the check depend on the waitcnt asm;
      //          sched_barrier pins ordering (rule #18).
      if (w == 0) {
        asm volatile("s_waitcnt vmcnt(17)" : "+v"(pv0) :: "memory");
        __builtin_amdgcn_sched_barrier(0);
        if (lane < 32 && pv0 == 0u) {
          const unsigned* fp = &flags[(size_t)(t - 1) * 128 + g * 32 + lane];
          int spin = 0;
          unsigned v;
          do {
            asm volatile("s_sleep 1\n\tglobal_load_dword %0, %1, off sc0\n\ts_waitcnt vmcnt(0)"
                         : "=v"(v) : "v"(fp) : "memory");
            if (v != 0u) break;               // per-lane exit; reconverge below
          } while (++spin < (1 << 15));       // cap: fail loud, never hang
        }
      }
      __syncthreads();
      // ---- (3) hidden GEMM; h via batched sc0 (L2-fresh) loads, Whh from LDS
      const unsigned short* hr0 = hc + (size_t)b0 * H_;
      bf16x8 ah[16];
      #pragma unroll
      for (int s = 0; s < 16; ++s) {
        asm volatile("global_load_dwordx4 %0, %1, off sc0"
                     : "=v"(ah[s]) : "v"(hr0 + s * 32 + quad * 8) : "memory");
      }
      asm volatile("s_waitcnt vmcnt(0)" ::: "memory");
      __builtin_amdgcn_sched_barrier(0);   // rule #18: pin MFMAs after the wait
      #pragma unroll
      for (int s = 0; s < 16; ++s) {
        acc_r = MFMA16(ah[s], wlds[3][s][lane], acc_r);
        acc_z = MFMA16(ah[s], wlds[4][s][lane], acc_z);
        acc_h = MFMA16(ah[s], wlds[5][s][lane], acc_h);
      }
    }

    // ---- (4) gates -> LDS tile repack -> coalesced u64 stores (L2-local)
    #pragma unroll
    for (int r = 0; r < 4; ++r) {
      int L = Lg[r];
      bool vld = t < L;
      float rr = sigm_f(acc_r[r] + b_r);
      float zz = sigm_f(acc_z[r] + b_z);
      float nn = tanh_f(acc_n[r] + b_in + rr * (acc_h[r] + b_hn));
      float hold = hreg[r];
      float hnew = vld ? ((1.f - zz) * nn + zz * hold) : hold;
      hreg[r] = hnew;
      unsigned short hbf = f2bf(hnew);
      htile[w][(4 * quad + r) * 16 + l15] = hbf;
      otile[w][(4 * quad + r) * 16 + l15] = vld ? hbf : (unsigned short)0;
    }
    asm volatile("s_waitcnt lgkmcnt(0)" ::: "memory");
    unsigned long long hv = *(const unsigned long long*)&htile[w][(lane >> 2) * 16 + jp * 4];
    unsigned long long ov = *(const unsigned long long*)&otile[w][(lane >> 2) * 16 + jp * 4];
    asm volatile("global_store_dwordx2 %0, %1, off sc0"
                 :: "v"(&hnx[(size_t)bs * H_ + j0 + jp * 4]), "v"(hv) : "memory");

    // ---- (5) arrive: barrier's implicit vmcnt drain covers the h stores of
    // all 4 waves; flag store follows (hits the warmed line); outb store is
    // issued AFTER (its ack overlaps the next step's poll wait).
    __syncthreads();
    if (tid == 0 && t < 511)
      asm volatile("global_store_dword %0, %1, off sc0"
                   :: "v"(&flags[(size_t)t * 128 + g * 32 + j5]), "v"(1u) : "memory");
    bool vs = t < Ls;
    int p = dir ? (vs ? (Ls - 1 - t) : t) : t;
    *(unsigned long long*)&outb[((size_t)bs * T_ + p) * 1024 + dir * 512 + j0 + jp * 4] = ov;
  }
}

// ---------------- K3: GEMM2 fused  sc4[cb] = sum_c tanh(out@Wp^T + bp) * ctx ----------------
__launch_bounds__(256)
__global__ void k_gemm2(const unsigned short* __restrict__ outbf,
                        const unsigned short* __restrict__ Wpb,
                        const float* __restrict__ bp, const float* __restrict__ ctx,
                        float* __restrict__ sc4) {     // [4][65536] partials
  __shared__ short smem[2 * 128 * 72];
  short* a_s = smem;
  short* b_s = smem + 128 * 72;
  int tid = threadIdx.x;
  int lane = tid & 63, w = tid >> 6;
  int quad = lane >> 4, l15 = lane & 15;
  int row0 = blockIdx.x * 128, col0 = blockIdx.y * 128;

  f32x4 acc[2][8];
  #pragma unroll
  for (int i = 0; i < 2; ++i)
    #pragma unroll
    for (int j = 0; j < 8; ++j) acc[i][j] = (f32x4){0.f, 0.f, 0.f, 0.f};

  for (int kt = 0; kt < 16; ++kt) {
    int k0 = kt * 64;
    __syncthreads();
    #pragma unroll
    for (int q = 0; q < 4; ++q) {
      int u = tid + 256 * q;
      int r = u >> 3, cu = u & 7;
      *(bf16x8*)&a_s[r * 72 + cu * 8] = *(const bf16x8*)&outbf[(size_t)(row0 + r) * 1024 + k0 + cu * 8];
      *(bf16x8*)&b_s[r * 72 + cu * 8] = *(const bf16x8*)&Wpb[(size_t)(col0 + r) * 1024 + k0 + cu * 8];
    }
    __syncthreads();
    #pragma unroll
    for (int kk = 0; kk < 2; ++kk) {
      int kb = kk * 32 + quad * 8;
      bf16x8 a0 = *(const bf16x8*)&a_s[(w * 32 + l15) * 72 + kb];
      bf16x8 a1 = *(const bf16x8*)&a_s[(w * 32 + 16 + l15) * 72 + kb];
      #pragma unroll
      for (int nt = 0; nt < 8; ++nt) {
        bf16x8 bb = *(const bf16x8*)&b_s[(nt * 16 + l15) * 72 + kb];
        acc[0][nt] = MFMA16(a0, bb, acc[0][nt]);
        acc[1][nt] = MFMA16(a1, bb, acc[1][nt]);
      }
    }
  }

  float rs[2][4] = {};
  #pragma unroll
  for (int mt = 0; mt < 2; ++mt) {
    #pragma unroll
    for (int nt = 0; nt < 8; ++nt) {
      int col = col0 + nt * 16 + l15;
      float bv = bp[col], cv = ctx[col];
      #pragma unroll
      for (int r = 0; r < 4; ++r) {
        float x = acc[mt][nt][r] + bv;
        rs[mt][r] += tanh_f(x) * cv;
      }
    }
  }
  #pragma unroll
  for (int mt = 0; mt < 2; ++mt) {
    #pragma unroll
    for (int r = 0; r < 4; ++r) {
      float v = rs[mt][r];
      v += __shfl_xor(v, 1); v += __shfl_xor(v, 2);
      v += __shfl_xor(v, 4); v += __shfl_xor(v, 8);
      if (l15 == 0)
        sc4[(size_t)blockIdx.y * 65536 + row0 + 32 * w + 16 * mt + 4 * quad + r] = v;
    }
  }
}

// ---------------- K4: masked softmax -> attn (output) ----------------
__launch_bounds__(64)
__global__ void k_softmax(const float* __restrict__ sc4, const int* __restrict__ lengths,
                          float* __restrict__ attn) {
  int b = blockIdx.x, lane = threadIdx.x;
  int L = lengths[b];
  float s[8]; float mx = -1e30f;
  #pragma unroll
  for (int i = 0; i < 8; ++i) {
    int t = lane + i * 64;
    int idx = b * T_ + t;
    float v = -1e30f;
    if (t < L)
      v = sc4[idx] + sc4[65536 + idx] + sc4[131072 + idx] + sc4[196608 + idx];
    s[i] = v;
    mx = fmaxf(mx, v);
  }
  #pragma unroll
  for (int o = 32; o; o >>= 1) mx = fmaxf(mx, __shfl_xor(mx, o));
  float sum = 0.f;
  #pragma unroll
  for (int i = 0; i < 8; ++i) {
    int t = lane + i * 64;
    s[i] = (t < L) ? __expf(s[i] - mx) : 0.f;
    sum += s[i];
  }
  #pragma unroll
  for (int o = 32; o; o >>= 1) sum += __shfl_xor(sum, o);
  float inv = 1.f / sum;
  #pragma unroll
  for (int i = 0; i < 8; ++i) attn[b * T_ + lane + i * 64] = s[i] * inv;
}

// ---------------- K5: attention pool + selu + classifier ----------------
__launch_bounds__(256)
__global__ void k_final(const float* __restrict__ attn, const unsigned short* __restrict__ outb,
                        const int* __restrict__ lengths,
                        const float* __restrict__ Wl, const float* __restrict__ bl,
                        float* __restrict__ logits) {
  __shared__ float red[8];
  int b = blockIdx.x, tid = threadIdx.x;
  int L = lengths[b];
  float a0 = 0.f, a1 = 0.f, a2 = 0.f, a3 = 0.f;
  for (int t = 0; t < L; ++t) {
    float a = attn[b * T_ + t];
    const unsigned short* row = outb + ((size_t)b * T_ + t) * 1024 + tid * 4;
    bf16x4 v = *(const bf16x4*)row;
    a0 += a * bf2f((unsigned short)v[0]);
    a1 += a * bf2f((unsigned short)v[1]);
    a2 += a * bf2f((unsigned short)v[2]);
    a3 += a * bf2f((unsigned short)v[3]);
  }
  const float al = 1.6732632423543772f, sc = 1.0507009873554805f;
  float s0 = sc * (a0 > 0.f ? a0 : al * (__expf(a0) - 1.f));
  float s1 = sc * (a1 > 0.f ? a1 : al * (__expf(a1) - 1.f));
  float s2 = sc * (a2 > 0.f ? a2 : al * (__expf(a2) - 1.f));
  float s3 = sc * (a3 > 0.f ? a3 : al * (__expf(a3) - 1.f));
  int d = tid * 4;
  float p0 = s0 * Wl[d] + s1 * Wl[d + 1] + s2 * Wl[d + 2] + s3 * Wl[d + 3];
  float p1 = s0 * Wl[1024 + d] + s1 * Wl[1024 + d + 1] + s2 * Wl[1024 + d + 2] + s3 * Wl[1024 + d + 3];
  #pragma unroll
  for (int o = 32; o; o >>= 1) { p0 += __shfl_xor(p0, o); p1 += __shfl_xor(p1, o); }
  if ((tid & 63) == 0) { red[(tid >> 6) * 2] = p0; red[(tid >> 6) * 2 + 1] = p1; }
  __syncthreads();
  if (tid == 0) {
    logits[b * 2]     = red[0] + red[2] + red[4] + red[6] + bl[0];
    logits[b * 2 + 1] = red[1] + red[3] + red[5] + red[7] + bl[1];
  }
}

// ---------------- launcher ----------------
extern "C" void kernel_launch(void* const* d_in, const int* in_sizes, int n_in,
                              void* d_out, int out_size, void* d_ws, size_t ws_size,
                              hipStream_t stream) {
  const int*   tokens  = (const int*)d_in[0];
  const int*   lengths = (const int*)d_in[1];
  const float* emb     = (const float*)d_in[2];
  const float* Wih_f   = (const float*)d_in[3];
  const float* Whh_f   = (const float*)d_in[4];
  const float* bih_f   = (const float*)d_in[5];
  const float* bhh_f   = (const float*)d_in[6];
  const float* Wih_b   = (const float*)d_in[7];
  const float* Whh_b   = (const float*)d_in[8];
  const float* bih_b   = (const float*)d_in[9];
  const float* bhh_b   = (const float*)d_in[10];
  const float* Wp      = (const float*)d_in[11];
  const float* bp      = (const float*)d_in[12];
  const float* ctx     = (const float*)d_in[13];
  const float* Wl      = (const float*)d_in[14];
  const float* bl      = (const float*)d_in[15];
  float* out = (float*)d_out;               // [0,256): logits, [256,65792): attn

  char* ws = (char*)d_ws;
  unsigned short* Wih  = (unsigned short*)(ws + 0);            //   3,145,728
  unsigned short* Whh  = (unsigned short*)(ws + 3145728);      //   3,145,728
  unsigned short* Wpb  = (unsigned short*)(ws + 6291456);      //   1,048,576
  unsigned short* xbf  = (unsigned short*)(ws + 7340032);      //  67,108,864
  unsigned short* outb = (unsigned short*)(ws + 74448896);     // 134,217,728
  unsigned short* hbuf = (unsigned short*)(ws + 208666624);    //     524,288
  float* sc4           = (float*)(ws + 209190912);             //   1,048,576
  unsigned* flags      = (unsigned*)(ws + 210239488);          //     262,144
  // total: 210,501,632 bytes

  k_cast<<<14336, 256, 0, stream>>>(Wih_f, Wih_b, Whh_f, Whh_b, Wp, Wih, Whh, Wpb, flags);
  k_gather<<<16384, 256, 0, stream>>>(tokens, emb, xbf);
  // 1024 blocks: first dispatch wave fills all 256 CUs (1 block/CU via LDS cap),
  // guaranteeing >=32 claimants per XCD; non-workers exit immediately.
  k_rec<<<1024, 256, 0, stream>>>(xbf, Wih, Whh, bih_f, bih_b, bhh_f, bhh_b,
                                  lengths, hbuf, outb, flags);
  dim3 g2(512, 4);
  k_gemm2<<<g2, 256, 0, stream>>>(outb, Wpb, bp, ctx, sc4);
  k_softmax<<<128, 64, 0, stream>>>(sc4, lengths, out + 256);
  k_final<<<128, 256, 0, stream>>>(out + 256, outb, lengths, Wl, bl, out);
}

// Round 12
// 3141.629 us; speedup vs baseline: 1.0597x; 1.0597x over previous
//
#include <hip/hip_runtime.h>
#include <stdint.h>

#define B_  128
#define T_  512
#define H_  512
#define G3  1536

typedef __attribute__((ext_vector_type(8))) short bf16x8;
typedef __attribute__((ext_vector_type(4))) short bf16x4;
typedef __attribute__((ext_vector_type(4))) float f32x4;

#define MFMA16(a,b,c) __builtin_amdgcn_mfma_f32_16x16x32_bf16((a),(b),(c),0,0,0)

__device__ __forceinline__ unsigned short f2bf(float f) {
  union { float f; unsigned u; } v; v.f = f;
  unsigned r = v.u + 0x7FFFu + ((v.u >> 16) & 1u);
  return (unsigned short)(r >> 16);
}
__device__ __forceinline__ float bf2f(unsigned short u) {
  union { unsigned u; float f; } v; v.u = ((unsigned)u) << 16; return v.f;
}
__device__ __forceinline__ float sigm_f(float x) { return 1.f / (1.f + __expf(-x)); }
__device__ __forceinline__ float tanh_f(float x) { float e = __expf(2.f * x); return 1.f - 2.f / (e + 1.f); }

// ---------------- K0: cast weights to bf16 + zero barrier flags ----------------
__launch_bounds__(256)
__global__ void k_cast(const float* __restrict__ Wih_f, const float* __restrict__ Wih_b,
                       const float* __restrict__ Whh_f, const float* __restrict__ Whh_b,
                       const float* __restrict__ Wp,
                       unsigned short* __restrict__ Wih, unsigned short* __restrict__ Whh,
                       unsigned short* __restrict__ Wpb, unsigned* __restrict__ flags) {
  int idx = blockIdx.x * 256 + threadIdx.x;
  if (idx < 65536) flags[idx] = 0;          // [T][128] flag rows; row 511 = ctrl
  if (idx < 1572864) {            // Wih: [2][1536][512]
    float v = (idx < 786432) ? Wih_f[idx] : Wih_b[idx - 786432];
    Wih[idx] = f2bf(v);
  } else if (idx < 3145728) {     // Whh: [2][1536][512]
    int i2 = idx - 1572864;
    float v = (i2 < 786432) ? Whh_f[i2] : Whh_b[i2 - 786432];
    Whh[i2] = f2bf(v);
  } else if (idx < 3670016) {     // Wp: [512][1024]
    int i3 = idx - 3145728;
    Wpb[i3] = f2bf(Wp[i3]);
  }
}

// ---------------- K1: gather embedding -> x_bf [65536][512] ----------------
__launch_bounds__(256)
__global__ void k_gather(const int* __restrict__ tokens, const float* __restrict__ emb,
                         unsigned short* __restrict__ xbf) {
  int row = blockIdx.x * 4 + (threadIdx.x >> 6);
  int lane = threadIdx.x & 63;
  int tok = tokens[row];
  const float4* src = (const float4*)(emb + (size_t)tok * 512);
  float4 v0 = src[lane * 2], v1 = src[lane * 2 + 1];
  bf16x8 pk;
  pk[0] = (short)f2bf(v0.x); pk[1] = (short)f2bf(v0.y);
  pk[2] = (short)f2bf(v0.z); pk[3] = (short)f2bf(v0.w);
  pk[4] = (short)f2bf(v1.x); pk[5] = (short)f2bf(v1.y);
  pk[6] = (short)f2bf(v1.z); pk[7] = (short)f2bf(v1.w);
  *(bf16x8*)&xbf[(size_t)row * 512 + lane * 8] = pk;
}

// ---------------- K2: persistent bidirectional GRU recurrence (XCD-local) ----
// FROZEN at proven v6 (3.09-3.12ms across R5/R8/R10/R11). Eleven rounds of
// mechanism-level interventions on this kernel's sync path (transport scope,
// poll shape/diet, flag packing/warming, store ordering, counted vmcnt,
// VALU & memory clock-keepers) were ALL neutral; the only real lever was
// traffic (weights->LDS, v6, -25%). The ~6us/step is a structural latency
// floor of the 32-fan-in per-step h-exchange. R7 lesson: x prefetch stays
// BEFORE the poll. This round's gains come from the post-recurrence kernels.
__launch_bounds__(256, 1)
__global__ void k_rec(const unsigned short* __restrict__ xbf,
                      const unsigned short* __restrict__ Wih,
                      const unsigned short* __restrict__ Whh,
                      const float* __restrict__ bih_f, const float* __restrict__ bih_b,
                      const float* __restrict__ bhh_f, const float* __restrict__ bhh_b,
                      const int* __restrict__ lengths,
                      unsigned short* __restrict__ hbuf,   // [2 buf][2 dir][128][512] bf16
                      unsigned short* __restrict__ outb,   // [65536][1024] bf16
                      unsigned* __restrict__ flags) {      // [512][128]; row 511 = ctrl
  __shared__ bf16x8 wlds[6][16][64];                 // 98304 B -> 1 block/CU
  __shared__ unsigned short htile[4][256];
  __shared__ unsigned short otile[4][256];
  __shared__ int role_s[2];

  unsigned* ctrl = flags + 511 * 128;

  if (threadIdx.x == 0) {
    unsigned xcd;
    asm volatile("s_getreg_b32 %0, hwreg(HW_REG_XCC_ID)" : "=s"(xcd));
    xcd &= 7u;
    unsigned slot = atomicAdd(&ctrl[xcd], 1u);      // device-scope (G12)
    unsigned gv;
    if (slot == 0u) {
      gv = atomicAdd(&ctrl[8], 1u) + 1u;            // this XCD claims a group
      __hip_atomic_store(&ctrl[16u + xcd], gv, __ATOMIC_RELAXED, __HIP_MEMORY_SCOPE_AGENT);
    } else {
      do {
        gv = __hip_atomic_load(&ctrl[16u + xcd], __ATOMIC_RELAXED, __HIP_MEMORY_SCOPE_AGENT);
      } while (gv == 0u);
    }
    int gq = (int)gv - 1;
    role_s[0] = (gq < 4 && slot < 32u) ? gq : -1;
    role_s[1] = (int)(slot & 31u);
  }
  __syncthreads();
  int g = role_s[0];
  if (g < 0) return;                  // surplus block or unclaimed XCD
  int j5 = role_s[1];

  int tid = threadIdx.x;
  int lane = tid & 63, w = tid >> 6;
  int quad = lane >> 4, l15 = lane & 15;
  int dir = g >> 1, mh = g & 1;
  int j0 = j5 << 4;
  int jg = j0 + l15;
  int rb = mh * 64 + w * 16;          // this wave's 16 batch rows

  const unsigned short* wih_g = Wih + (size_t)dir * (G3 * H_);
  const unsigned short* whh_g = Whh + (size_t)dir * (G3 * H_);
  const float* bih = dir ? bih_b : bih_f;
  const float* bhh = dir ? bhh_b : bhh_f;
  float b_r  = bih[jg] + bhh[jg];
  float b_z  = bih[512 + jg] + bhh[512 + jg];
  float b_in = bih[1024 + jg];
  float b_hn = bhh[1024 + jg];

  // ---- stage all 6 gate-weight fragment tables into LDS (one time) ----
  for (int gi = w; gi < 6; gi += 4) {
    const unsigned short* base =
        (gi < 3 ? wih_g : whh_g) + (size_t)((gi % 3) * 512 + j0 + (lane & 15)) * 512;
    for (int s = 0; s < 16; ++s)
      wlds[gi][s][lane] = *(const bf16x8*)&base[s * 32 + (lane >> 4) * 8];
  }
  __syncthreads();

  int b0 = rb + l15;                 // A-frag row
  int L0 = lengths[b0];
  int Lg[4];
  #pragma unroll
  for (int r = 0; r < 4; ++r) Lg[r] = lengths[rb + 4 * quad + r];
  int bs = rb + (lane >> 2);         // store-phase row
  int Ls = lengths[bs];
  int jp = lane & 3;

  unsigned short* hb = hbuf + (size_t)dir * (B_ * H_);
  float hreg[4] = {};                // f32 master copy of own (b, j) hidden state

  // prologue: x fragments for t=0
  bf16x8 ax[16];
  {
    int tx0 = dir ? (L0 - 1) : 0;    // L0 >= T/2 >= 1
    const unsigned short* xr = xbf + ((size_t)b0 * T_ + tx0) * 512;
    #pragma unroll
    for (int s = 0; s < 16; ++s) ax[s] = *(const bf16x8*)&xr[s * 32 + quad * 8];
  }

  #pragma clang loop unroll(disable)
  for (int t = 0; t < T_; ++t) {
    const unsigned short* hc = hb + (size_t)(t & 1) * (2 * B_ * H_);
    unsigned short* hnx      = hb + (size_t)((t & 1) ^ 1) * (2 * B_ * H_);

    f32x4 acc_r = {0.f,0.f,0.f,0.f}, acc_z = {0.f,0.f,0.f,0.f};
    f32x4 acc_n = {0.f,0.f,0.f,0.f}, acc_h = {0.f,0.f,0.f,0.f};

    // ---- (1) input GEMM for step t: x from regs, Wih from LDS
    #pragma unroll
    for (int s = 0; s < 16; ++s) {
      acc_r = MFMA16(ax[s], wlds[0][s][lane], acc_r);
      acc_z = MFMA16(ax[s], wlds[1][s][lane], acc_z);
      acc_n = MFMA16(ax[s], wlds[2][s][lane], acc_n);
    }
    // ---- (1b) prefetch x for t+1 BEFORE the poll (R7: after = 2.7x regress)
    {
      int tn = (t + 1 < T_) ? (t + 1) : t;
      int tx1 = dir ? ((tn < L0) ? (L0 - 1 - tn) : 0) : tn;
      const unsigned short* xr1 = xbf + ((size_t)b0 * T_ + tx1) * 512;
      #pragma unroll
      for (int s = 0; s < 16; ++s) ax[s] = *(const bf16x8*)&xr1[s * 32 + quad * 8];
    }

    if (t > 0) {
      // ---- (2) wait for h_{t-1}: wave 0, one lane per flag, backoff + cap
      if (w == 0 && lane < 32) {
        const unsigned* fp = &flags[(size_t)(t - 1) * 128 + g * 32 + lane];
        int spin = 0;
        unsigned v;
        do {
          asm volatile("global_load_dword %0, %1, off sc0\n\ts_waitcnt vmcnt(0)"
                       : "=v"(v) : "v"(fp) : "memory");
          if (v != 0u) break;                 // per-lane exit; reconverge below
          asm volatile("s_sleep 1" ::: "memory");
        } while (++spin < (1 << 15));         // cap: fail loud, never hang
      }
      __syncthreads();
      // ---- (3) hidden GEMM; h via batched sc0 (L2-fresh) loads, Whh from LDS
      const unsigned short* hr0 = hc + (size_t)b0 * H_;
      bf16x8 ah[16];
      #pragma unroll
      for (int s = 0; s < 16; ++s) {
        asm volatile("global_load_dwordx4 %0, %1, off sc0"
                     : "=v"(ah[s]) : "v"(hr0 + s * 32 + quad * 8) : "memory");
      }
      asm volatile("s_waitcnt vmcnt(0)" ::: "memory");
      __builtin_amdgcn_sched_barrier(0);   // rule #18: pin MFMAs after the wait
      #pragma unroll
      for (int s = 0; s < 16; ++s) {
        acc_r = MFMA16(ah[s], wlds[3][s][lane], acc_r);
        acc_z = MFMA16(ah[s], wlds[4][s][lane], acc_z);
        acc_h = MFMA16(ah[s], wlds[5][s][lane], acc_h);
      }
    }

    // ---- (4) gates -> LDS tile repack -> coalesced u64 stores (L2-local)
    #pragma unroll
    for (int r = 0; r < 4; ++r) {
      int L = Lg[r];
      bool vld = t < L;
      float rr = sigm_f(acc_r[r] + b_r);
      float zz = sigm_f(acc_z[r] + b_z);
      float nn = tanh_f(acc_n[r] + b_in + rr * (acc_h[r] + b_hn));
      float hold = hreg[r];
      float hnew = vld ? ((1.f - zz) * nn + zz * hold) : hold;
      hreg[r] = hnew;
      unsigned short hbf = f2bf(hnew);
      htile[w][(4 * quad + r) * 16 + l15] = hbf;
      otile[w][(4 * quad + r) * 16 + l15] = vld ? hbf : (unsigned short)0;
    }
    asm volatile("s_waitcnt lgkmcnt(0)" ::: "memory");
    unsigned long long hv = *(const unsigned long long*)&htile[w][(lane >> 2) * 16 + jp * 4];
    unsigned long long ov = *(const unsigned long long*)&otile[w][(lane >> 2) * 16 + jp * 4];
    asm volatile("global_store_dwordx2 %0, %1, off sc0"
                 :: "v"(&hnx[(size_t)bs * H_ + j0 + jp * 4]), "v"(hv) : "memory");

    // ---- (5) arrive: barrier's implicit vmcnt drain covers the h stores of
    // all 4 waves; flag store follows; outb store is issued AFTER (its ack
    // overlaps the next step's poll wait instead of gating the flag).
    __syncthreads();
    if (tid == 0 && t < 511)
      asm volatile("global_store_dword %0, %1, off sc0"
                   :: "v"(&flags[(size_t)t * 128 + g * 32 + j5]), "v"(1u) : "memory");
    bool vs = t < Ls;
    int p = dir ? (vs ? (Ls - 1 - t) : t) : t;
    *(unsigned long long*)&outb[((size_t)bs * T_ + p) * 1024 + dir * 512 + j0 + jp * 4] = ov;
  }
}

// ---------------- K3: GEMM2 fused  sc4[cb] = sum_c tanh(out@Wp^T + bp) * ctx --
// R11 counter read: grid (512,4) dispatched the 4 col-blocks sharing a
// 256KB outb row-panel 512 blocks apart -> panels re-fetched (FETCH 266MB,
// 22% HBM, 155us). Grid FLIPPED to (4,512): x varies fastest, so the 4
// sharers dispatch adjacently, co-reside, and the panel is read once into
// L2/L3 and shared. Kernel body identical; only the blockIdx mapping moved.
__launch_bounds__(256)
__global__ void k_gemm2(const unsigned short* __restrict__ outbf,
                        const unsigned short* __restrict__ Wpb,
                        const float* __restrict__ bp, const float* __restrict__ ctx,
                        float* __restrict__ sc4) {     // [4][65536] partials
  __shared__ short smem[2 * 128 * 72];
  short* a_s = smem;
  short* b_s = smem + 128 * 72;
  int tid = threadIdx.x;
  int lane = tid & 63, w = tid >> 6;
  int quad = lane >> 4, l15 = lane & 15;
  int cg = blockIdx.x;                       // col-group 0..3 (fastest)
  int row0 = blockIdx.y * 128, col0 = cg * 128;

  f32x4 acc[2][8];
  #pragma unroll
  for (int i = 0; i < 2; ++i)
    #pragma unroll
    for (int j = 0; j < 8; ++j) acc[i][j] = (f32x4){0.f, 0.f, 0.f, 0.f};

  for (int kt = 0; kt < 16; ++kt) {
    int k0 = kt * 64;
    __syncthreads();
    #pragma unroll
    for (int q = 0; q < 4; ++q) {
      int u = tid + 256 * q;
      int r = u >> 3, cu = u & 7;
      *(bf16x8*)&a_s[r * 72 + cu * 8] = *(const bf16x8*)&outbf[(size_t)(row0 + r) * 1024 + k0 + cu * 8];
      *(bf16x8*)&b_s[r * 72 + cu * 8] = *(const bf16x8*)&Wpb[(size_t)(col0 + r) * 1024 + k0 + cu * 8];
    }
    __syncthreads();
    #pragma unroll
    for (int kk = 0; kk < 2; ++kk) {
      int kb = kk * 32 + quad * 8;
      bf16x8 a0 = *(const bf16x8*)&a_s[(w * 32 + l15) * 72 + kb];
      bf16x8 a1 = *(const bf16x8*)&a_s[(w * 32 + 16 + l15) * 72 + kb];
      #pragma unroll
      for (int nt = 0; nt < 8; ++nt) {
        bf16x8 bb = *(const bf16x8*)&b_s[(nt * 16 + l15) * 72 + kb];
        acc[0][nt] = MFMA16(a0, bb, acc[0][nt]);
        acc[1][nt] = MFMA16(a1, bb, acc[1][nt]);
      }
    }
  }

  float rs[2][4] = {};
  #pragma unroll
  for (int mt = 0; mt < 2; ++mt) {
    #pragma unroll
    for (int nt = 0; nt < 8; ++nt) {
      int col = col0 + nt * 16 + l15;
      float bv = bp[col], cv = ctx[col];
      #pragma unroll
      for (int r = 0; r < 4; ++r) {
        float x = acc[mt][nt][r] + bv;
        rs[mt][r] += tanh_f(x) * cv;
      }
    }
  }
  #pragma unroll
  for (int mt = 0; mt < 2; ++mt) {
    #pragma unroll
    for (int r = 0; r < 4; ++r) {
      float v = rs[mt][r];
      v += __shfl_xor(v, 1); v += __shfl_xor(v, 2);
      v += __shfl_xor(v, 4); v += __shfl_xor(v, 8);
      if (l15 == 0)
        sc4[(size_t)cg * 65536 + row0 + 32 * w + 16 * mt + 4 * quad + r] = v;
    }
  }
}

// ---------------- K4: masked softmax -> attn (output) ----------------
__launch_bounds__(64)
__global__ void k_softmax(const float* __restrict__ sc4, const int* __restrict__ lengths,
                          float* __restrict__ attn) {
  int b = blockIdx.x, lane = threadIdx.x;
  int L = lengths[b];
  float s[8]; float mx = -1e30f;
  #pragma unroll
  for (int i = 0; i < 8; ++i) {
    int t = lane + i * 64;
    int idx = b * T_ + t;
    float v = -1e30f;
    if (t < L)
      v = sc4[idx] + sc4[65536 + idx] + sc4[131072 + idx] + sc4[196608 + idx];
    s[i] = v;
    mx = fmaxf(mx, v);
  }
  #pragma unroll
  for (int o = 32; o; o >>= 1) mx = fmaxf(mx, __shfl_xor(mx, o));
  float sum = 0.f;
  #pragma unroll
  for (int i = 0; i < 8; ++i) {
    int t = lane + i * 64;
    s[i] = (t < L) ? __expf(s[i] - mx) : 0.f;
    sum += s[i];
  }
  #pragma unroll
  for (int o = 32; o; o >>= 1) sum += __shfl_xor(sum, o);
  float inv = 1.f / sum;
  #pragma unroll
  for (int i = 0; i < 8; ++i) attn[b * T_ + lane + i * 64] = s[i] * inv;
}

// ---------------- K5a: attention-pool partials (t-split 8-way) ---------------
// R11 counter read: old k_final = 128 blocks x serial 512-iteration latency
// chain (1 attn scalar + 1KB row per iter ~ 260cy) = 134us. Split the t-loop
// across 8 blocks per batch row (grid 1024): 8x memory-level parallelism,
// partials into the DEAD xbf region (k_rec done; zero extra workspace).
// Unconditional t-slices are numerically identical: attn[b,t>=L] == 0.0f
// exactly (k_softmax zeroes masked terms) and outb rows there are 0.
__launch_bounds__(256)
__global__ void k_fpart(const float* __restrict__ attn, const unsigned short* __restrict__ outb,
                        float* __restrict__ part) {    // [1024][1024] f32
  int b = blockIdx.x >> 3, s = blockIdx.x & 7;
  int tid = threadIdx.x;
  float a0 = 0.f, a1 = 0.f, a2 = 0.f, a3 = 0.f;
  int t0 = s * 64;
  #pragma unroll 4
  for (int i = 0; i < 64; ++i) {
    int t = t0 + i;
    float a = attn[b * T_ + t];
    bf16x4 v = *(const bf16x4*)(outb + ((size_t)b * T_ + t) * 1024 + tid * 4);
    a0 += a * bf2f((unsigned short)v[0]);
    a1 += a * bf2f((unsigned short)v[1]);
    a2 += a * bf2f((unsigned short)v[2]);
    a3 += a * bf2f((unsigned short)v[3]);
  }
  float4 st = {a0, a1, a2, a3};
  *(float4*)&part[(size_t)blockIdx.x * 1024 + tid * 4] = st;
}

// ---------------- K5b: reduce partials + selu + classifier -------------------
__launch_bounds__(256)
__global__ void k_fred(const float* __restrict__ part,
                       const float* __restrict__ Wl, const float* __restrict__ bl,
                       float* __restrict__ logits) {
  __shared__ float red[8];
  int b = blockIdx.x, tid = threadIdx.x;
  float a0 = 0.f, a1 = 0.f, a2 = 0.f, a3 = 0.f;
  #pragma unroll
  for (int s = 0; s < 8; ++s) {
    float4 v = *(const float4*)&part[(size_t)(b * 8 + s) * 1024 + tid * 4];
    a0 += v.x; a1 += v.y; a2 += v.z; a3 += v.w;
  }
  const float al = 1.6732632423543772f, sc = 1.0507009873554805f;
  float s0 = sc * (a0 > 0.f ? a0 : al * (__expf(a0) - 1.f));
  float s1 = sc * (a1 > 0.f ? a1 : al * (__expf(a1) - 1.f));
  float s2 = sc * (a2 > 0.f ? a2 : al * (__expf(a2) - 1.f));
  float s3 = sc * (a3 > 0.f ? a3 : al * (__expf(a3) - 1.f));
  int d = tid * 4;
  float p0 = s0 * Wl[d] + s1 * Wl[d + 1] + s2 * Wl[d + 2] + s3 * Wl[d + 3];
  float p1 = s0 * Wl[1024 + d] + s1 * Wl[1024 + d + 1] + s2 * Wl[1024 + d + 2] + s3 * Wl[1024 + d + 3];
  #pragma unroll
  for (int o = 32; o; o >>= 1) { p0 += __shfl_xor(p0, o); p1 += __shfl_xor(p1, o); }
  if ((tid & 63) == 0) { red[(tid >> 6) * 2] = p0; red[(tid >> 6) * 2 + 1] = p1; }
  __syncthreads();
  if (tid == 0) {
    logits[b * 2]     = red[0] + red[2] + red[4] + red[6] + bl[0];
    logits[b * 2 + 1] = red[1] + red[3] + red[5] + red[7] + bl[1];
  }
}

// ---------------- launcher ----------------
extern "C" void kernel_launch(void* const* d_in, const int* in_sizes, int n_in,
                              void* d_out, int out_size, void* d_ws, size_t ws_size,
                              hipStream_t stream) {
  const int*   tokens  = (const int*)d_in[0];
  const int*   lengths = (const int*)d_in[1];
  const float* emb     = (const float*)d_in[2];
  const float* Wih_f   = (const float*)d_in[3];
  const float* Whh_f   = (const float*)d_in[4];
  const float* bih_f   = (const float*)d_in[5];
  const float* bhh_f   = (const float*)d_in[6];
  const float* Wih_b   = (const float*)d_in[7];
  const float* Whh_b   = (const float*)d_in[8];
  const float* bih_b   = (const float*)d_in[9];
  const float* bhh_b   = (const float*)d_in[10];
  const float* Wp      = (const float*)d_in[11];
  const float* bp      = (const float*)d_in[12];
  const float* ctx     = (const float*)d_in[13];
  const float* Wl      = (const float*)d_in[14];
  const float* bl      = (const float*)d_in[15];
  float* out = (float*)d_out;               // [0,256): logits, [256,65792): attn

  char* ws = (char*)d_ws;
  unsigned short* Wih  = (unsigned short*)(ws + 0);            //   3,145,728
  unsigned short* Whh  = (unsigned short*)(ws + 3145728);      //   3,145,728
  unsigned short* Wpb  = (unsigned short*)(ws + 6291456);      //   1,048,576
  unsigned short* xbf  = (unsigned short*)(ws + 7340032);      //  67,108,864
  unsigned short* outb = (unsigned short*)(ws + 74448896);     // 134,217,728
  unsigned short* hbuf = (unsigned short*)(ws + 208666624);    //     524,288
  float* sc4           = (float*)(ws + 209190912);             //   1,048,576
  unsigned* flags      = (unsigned*)(ws + 210239488);          //     262,144
  // total: 210,501,632 bytes (proven to fit)
  float* part          = (float*)(ws + 7340032);               // aliases xbf (dead after k_rec)

  k_cast<<<14336, 256, 0, stream>>>(Wih_f, Wih_b, Whh_f, Whh_b, Wp, Wih, Whh, Wpb, flags);
  k_gather<<<16384, 256, 0, stream>>>(tokens, emb, xbf);
  // 1024 blocks: first dispatch wave fills all 256 CUs (1 block/CU via LDS cap),
  // guaranteeing >=32 claimants per XCD; non-workers exit immediately.
  k_rec<<<1024, 256, 0, stream>>>(xbf, Wih, Whh, bih_f, bih_b, bhh_f, bhh_b,
                                  lengths, hbuf, outb, flags);
  dim3 g2(4, 512);   // x fastest: the 4 col-blocks sharing a row-panel co-reside
  k_gemm2<<<g2, 256, 0, stream>>>(outb, Wpb, bp, ctx, sc4);
  k_softmax<<<128, 64, 0, stream>>>(sc4, lengths, out + 256);
  k_fpart<<<1024, 256, 0, stream>>>(out + 256, outb, part);
  k_fred<<<128, 256, 0, stream>>>(part, Wl, bl, out);
}